// Round 1
// baseline (3077.310 us; speedup 1.0000x reference)
//
#include <hip/hip_runtime.h>
#include <math.h>

#define NB 2048      // batch
#define KN 20        // neighbors
#define DD 128       // edge feat dim
#define TT 100       // time dim
#define CC 128       // channels
#define TKN 40       // tokens (2K)
#define HTD 20       // token FFN hidden
#define HCD 512      // channel FFN hidden
#define NXS 132      // padded LDS row stride (128+4)

__device__ __forceinline__ float gelu_f(float x) {
    return 0.5f * x * (1.0f + erff(x * 0.70710678118654752f));
}

// ---------------------------------------------------------------------------
// Kernel 1: build tokens for both branches.
// grid (NB, 2), block 128. Two passes of 20 tokens (pass == eproj half).
// ---------------------------------------------------------------------------
__global__ __launch_bounds__(128) void build_tokens(
    const float* __restrict__ edge_table,
    const int* __restrict__ src_eids, const int* __restrict__ dst_eids,
    const int* __restrict__ src2_e1, const int* __restrict__ src2_e2,
    const int* __restrict__ dst2_e1, const int* __restrict__ dst2_e2,
    const float* __restrict__ dt_src, const float* __restrict__ dt_dst,
    const float* __restrict__ dt2_src, const float* __restrict__ dt2_dst,
    const float* __restrict__ time_w, const float* __restrict__ time_b,
    const float* __restrict__ proj_W, const float* __restrict__ proj_b,
    const float* __restrict__ eproj_W, const float* __restrict__ eproj_b,
    float* __restrict__ tok)
{
    const int b = blockIdx.x;
    const int branch = blockIdx.y;
    const int tid = threadIdx.x;
    const int lane = tid & 63;
    const int wv = tid >> 6;            // 0..1
    const int Kdim = (branch == 0) ? (DD + TT) : (3 * DD + TT);   // 228 / 484
    const int FS = 488;                 // feat row stride (multiple of 4)

    __shared__ float feat[20 * 488];    // 39 KB

    float* tokp = tok + ((size_t)branch * NB + b) * TKN * CC;

    for (int pass = 0; pass < 2; ++pass) {
        // ---- fill feats for tokens pass*20 .. pass*20+19 ----
        for (int tt = 0; tt < 10; ++tt) {
            const int tl = wv * 10 + tt;        // 0..19 local row
            const int t = pass * 20 + tl;       // global token 0..39
            const int kk = (t < KN) ? t : (t - KN);
            float* f = feat + tl * FS;
            if (branch == 0) {
                int eid; float dt;
                if (t < KN) { eid = src_eids[b * KN + kk]; dt = dt_src[b * KN + kk]; }
                else        { eid = dst_eids[b * KN + kk]; dt = dt_dst[b * KN + kk]; }
                const float* er = edge_table + (size_t)eid * DD;
                f[lane] = er[lane];
                f[lane + 64] = er[lane + 64];
                const float msk = (eid == 0) ? 0.0f : 1.0f;
                f[DD + lane] = msk * cosf(dt * time_w[lane] + time_b[lane]);
                if (lane < TT - 64)
                    f[DD + 64 + lane] = msk * cosf(dt * time_w[64 + lane] + time_b[64 + lane]);
            } else {
                int e1, e2, e0; float dt;
                if (t < KN) {
                    e1 = src2_e1[b * KN + kk]; e2 = src2_e2[b * KN + kk];
                    e0 = src_eids[b * KN + kk]; dt = dt2_src[b * KN + kk];
                } else {
                    e1 = dst2_e1[b * KN + kk]; e2 = dst2_e2[b * KN + kk];
                    e0 = dst_eids[b * KN + kk]; dt = dt2_dst[b * KN + kk];
                }
                const float* r1 = edge_table + (size_t)e1 * DD;
                const float* r2 = edge_table + (size_t)e2 * DD;
                const float* r0 = edge_table + (size_t)e0 * DD;
                f[lane] = r1[lane];             f[lane + 64] = r1[lane + 64];
                f[DD + lane] = r2[lane];        f[DD + lane + 64] = r2[lane + 64];
                f[2 * DD + lane] = r0[lane];    f[2 * DD + lane + 64] = r0[lane + 64];
                const float msk = (e1 == 0) ? 0.0f : 1.0f;   // mask on e1 ids (ref: tenc(dt, e1ids))
                f[3 * DD + lane] = msk * cosf(dt * time_w[lane] + time_b[lane]);
                if (lane < TT - 64)
                    f[3 * DD + 64 + lane] = msk * cosf(dt * time_w[64 + lane] + time_b[64 + lane]);
            }
        }
        __syncthreads();

        // ---- GEMM [20 x Kdim] x [Kdim x 128] ----
        const int tg = tid >> 5;        // 0..3
        const int cg = tid & 31;        // 0..31
        const int t5 = tg * 5;
        const int c4 = cg * 4;
        const float* Wp; const float* bp;
        if (branch == 0) { Wp = proj_W; bp = proj_b; }
        else { Wp = eproj_W + (size_t)pass * (3 * DD + TT) * CC; bp = eproj_b + pass * CC; }

        float acc[5][4];
        #pragma unroll
        for (int i = 0; i < 5; ++i)
            #pragma unroll
            for (int j = 0; j < 4; ++j) acc[i][j] = 0.0f;

        for (int kc = 0; kc < Kdim; kc += 4) {
            float w[4][4];
            #pragma unroll
            for (int kkk = 0; kkk < 4; ++kkk) {
                const float4 t4 = *(const float4*)(Wp + (size_t)(kc + kkk) * CC + c4);
                w[kkk][0] = t4.x; w[kkk][1] = t4.y; w[kkk][2] = t4.z; w[kkk][3] = t4.w;
            }
            #pragma unroll
            for (int i = 0; i < 5; ++i) {
                const float4 f4 = *(const float4*)(feat + (t5 + i) * FS + kc);
                const float fv[4] = {f4.x, f4.y, f4.z, f4.w};
                #pragma unroll
                for (int kkk = 0; kkk < 4; ++kkk)
                    #pragma unroll
                    for (int j = 0; j < 4; ++j)
                        acc[i][j] += fv[kkk] * w[kkk][j];
            }
        }
        #pragma unroll
        for (int i = 0; i < 5; ++i)
            #pragma unroll
            for (int j = 0; j < 4; ++j)
                tokp[(size_t)(pass * 20 + t5 + i) * CC + c4 + j] = acc[i][j] + bp[c4 + j];
        __syncthreads();
    }
}

// ---------------------------------------------------------------------------
// Kernel 2: token mixing. grid (NB,2), block 128 (thread = channel).
// x += FFN(LN_token(x^T))^T, in place.
// ---------------------------------------------------------------------------
__global__ __launch_bounds__(128) void token_mix(
    float* __restrict__ tok, int layer,
    const float* __restrict__ tln_g, const float* __restrict__ tln_b,
    const float* __restrict__ tW1, const float* __restrict__ tb1,
    const float* __restrict__ tW2, const float* __restrict__ tb2)
{
    const int b = blockIdx.x;
    const int branch = blockIdx.y;
    const int m = branch * 2 + layer;   // mixer index
    const int c = threadIdx.x;          // 0..127

    const float* g  = tln_g + m * TKN;
    const float* bb = tln_b + m * TKN;
    const float* W1 = tW1 + (size_t)m * TKN * HTD;
    const float* b1 = tb1 + m * HTD;
    const float* W2 = tW2 + (size_t)m * HTD * TKN;
    const float* b2 = tb2 + m * TKN;

    float* xp = tok + ((size_t)branch * NB + b) * TKN * CC;

    float v[TKN];
    float s = 0.0f;
    #pragma unroll
    for (int k = 0; k < TKN; ++k) { v[k] = xp[k * CC + c]; s += v[k]; }
    const float mean = s * (1.0f / TKN);
    float vs = 0.0f;
    #pragma unroll
    for (int k = 0; k < TKN; ++k) { const float d = v[k] - mean; vs += d * d; }
    const float rinv = rsqrtf(vs * (1.0f / TKN) + 1e-5f);

    float h1[HTD];
    #pragma unroll
    for (int j = 0; j < HTD; ++j) h1[j] = b1[j];
    for (int k = 0; k < TKN; ++k) {
        const float nk = (v[k] - mean) * rinv * g[k] + bb[k];
        #pragma unroll
        for (int j = 0; j < HTD; ++j) h1[j] += nk * W1[k * HTD + j];
    }
    #pragma unroll
    for (int j = 0; j < HTD; ++j) h1[j] = gelu_f(h1[j]);

    for (int k = 0; k < TKN; ++k) {
        float s2 = b2[k];
        #pragma unroll
        for (int j = 0; j < HTD; ++j) s2 += h1[j] * W2[j * TKN + k];
        xp[k * CC + c] = v[k] + s2;
    }
}

// ---------------------------------------------------------------------------
// Kernel 3: channel mixing. grid (NB,2), block 128.
// x += FFN2(LN_chan(x)), hidden 512 staged in 4 LDS chunks of 128.
// ---------------------------------------------------------------------------
__global__ __launch_bounds__(128) void channel_mix(
    float* __restrict__ tok, int layer,
    const float* __restrict__ cln_g, const float* __restrict__ cln_b,
    const float* __restrict__ cW1, const float* __restrict__ cb1,
    const float* __restrict__ cW2, const float* __restrict__ cb2)
{
    const int b = blockIdx.x;
    const int branch = blockIdx.y;
    const int m = branch * 2 + layer;
    const int tid = threadIdx.x;
    const int lane = tid & 63;
    const int wv = tid >> 6;            // 0..1

    const float* g  = cln_g + m * CC;
    const float* bb = cln_b + m * CC;
    const float* W1 = cW1 + (size_t)m * CC * HCD;
    const float* B1 = cb1 + m * HCD;
    const float* W2 = cW2 + (size_t)m * HCD * CC;
    const float* B2 = cb2 + m * CC;

    float* xp = tok + ((size_t)branch * NB + b) * TKN * CC;

    __shared__ float nx[TKN * NXS];     // LN'd input, padded stride
    __shared__ float hb[TKN * NXS];     // hidden chunk, padded stride

    // ---- LN per token (wave handles alternating tokens) ----
    for (int t = wv; t < TKN; t += 2) {
        const float x0 = xp[t * CC + lane];
        const float x1 = xp[t * CC + lane + 64];
        float s = x0 + x1;
        float q = x0 * x0 + x1 * x1;
        #pragma unroll
        for (int o = 32; o > 0; o >>= 1) {
            s += __shfl_xor(s, o);
            q += __shfl_xor(q, o);
        }
        const float mean = s * (1.0f / CC);
        const float var = q * (1.0f / CC) - mean * mean;
        const float rinv = rsqrtf(var + 1e-5f);
        nx[t * NXS + lane]      = (x0 - mean) * rinv * g[lane] + bb[lane];
        nx[t * NXS + lane + 64] = (x1 - mean) * rinv * g[lane + 64] + bb[lane + 64];
    }
    __syncthreads();

    // thread tile: [5 tokens x 8 cols]
    const int tg = tid >> 4;            // 0..7
    const int cg = tid & 15;            // 0..15
    const int t5 = tg * 5;
    const int c8 = cg * 8;

    float acc2[5][8];
    #pragma unroll
    for (int i = 0; i < 5; ++i)
        #pragma unroll
        for (int j = 0; j < 8; ++j) acc2[i][j] = 0.0f;

    for (int hc = 0; hc < 4; ++hc) {
        const int hcol0 = hc * 128 + c8;

        // ---- GEMM1: h = gelu(nx @ W1[:, hc*128 : hc*128+128] + b1) ----
        float acc1[5][8];
        #pragma unroll
        for (int i = 0; i < 5; ++i)
            #pragma unroll
            for (int j = 0; j < 8; ++j) acc1[i][j] = 0.0f;

        for (int kc = 0; kc < 32; ++kc) {
            float w[4][8];
            #pragma unroll
            for (int kkk = 0; kkk < 4; ++kkk) {
                const float* wrow = W1 + (size_t)(4 * kc + kkk) * HCD + hcol0;
                const float4 a0 = *(const float4*)(wrow);
                const float4 a1 = *(const float4*)(wrow + 4);
                w[kkk][0] = a0.x; w[kkk][1] = a0.y; w[kkk][2] = a0.z; w[kkk][3] = a0.w;
                w[kkk][4] = a1.x; w[kkk][5] = a1.y; w[kkk][6] = a1.z; w[kkk][7] = a1.w;
            }
            #pragma unroll
            for (int i = 0; i < 5; ++i) {
                const float4 f4 = *(const float4*)(nx + (t5 + i) * NXS + 4 * kc);
                const float fv[4] = {f4.x, f4.y, f4.z, f4.w};
                #pragma unroll
                for (int kkk = 0; kkk < 4; ++kkk)
                    #pragma unroll
                    for (int j = 0; j < 8; ++j)
                        acc1[i][j] += fv[kkk] * w[kkk][j];
            }
        }

        __syncthreads();   // previous chunk's GEMM2 readers done with hb
        #pragma unroll
        for (int i = 0; i < 5; ++i)
            #pragma unroll
            for (int j = 0; j < 8; ++j)
                hb[(t5 + i) * NXS + c8 + j] = gelu_f(acc1[i][j] + B1[hcol0 + j]);
        __syncthreads();

        // ---- GEMM2: acc2 += h @ W2[hc*128 : hc*128+128, :] ----
        for (int kc = 0; kc < 32; ++kc) {
            float w[4][8];
            #pragma unroll
            for (int kkk = 0; kkk < 4; ++kkk) {
                const float* wrow = W2 + (size_t)(hc * 128 + 4 * kc + kkk) * CC + c8;
                const float4 a0 = *(const float4*)(wrow);
                const float4 a1 = *(const float4*)(wrow + 4);
                w[kkk][0] = a0.x; w[kkk][1] = a0.y; w[kkk][2] = a0.z; w[kkk][3] = a0.w;
                w[kkk][4] = a1.x; w[kkk][5] = a1.y; w[kkk][6] = a1.z; w[kkk][7] = a1.w;
            }
            #pragma unroll
            for (int i = 0; i < 5; ++i) {
                const float4 f4 = *(const float4*)(hb + (t5 + i) * NXS + 4 * kc);
                const float fv[4] = {f4.x, f4.y, f4.z, f4.w};
                #pragma unroll
                for (int kkk = 0; kkk < 4; ++kkk)
                    #pragma unroll
                    for (int j = 0; j < 8; ++j)
                        acc2[i][j] += fv[kkk] * w[kkk][j];
            }
        }
    }

    // ---- residual + bias, write back ----
    #pragma unroll
    for (int i = 0; i < 5; ++i) {
        float* row = xp + (size_t)(t5 + i) * CC + c8;
        const float4 x0 = *(const float4*)(row);
        const float4 x1 = *(const float4*)(row + 4);
        float4 o0, o1;
        o0.x = x0.x + acc2[i][0] + B2[c8 + 0];
        o0.y = x0.y + acc2[i][1] + B2[c8 + 1];
        o0.z = x0.z + acc2[i][2] + B2[c8 + 2];
        o0.w = x0.w + acc2[i][3] + B2[c8 + 3];
        o1.x = x1.x + acc2[i][4] + B2[c8 + 4];
        o1.y = x1.y + acc2[i][5] + B2[c8 + 5];
        o1.z = x1.z + acc2[i][6] + B2[c8 + 6];
        o1.w = x1.w + acc2[i][7] + B2[c8 + 7];
        *(float4*)(row) = o0;
        *(float4*)(row + 4) = o1;
    }
}

// ---------------------------------------------------------------------------
// Kernel 4: token mean + pcc softmax blend. grid NB, block 128.
// ---------------------------------------------------------------------------
__global__ __launch_bounds__(128) void combine(
    const float* __restrict__ tok,
    const float* __restrict__ pcc1, const float* __restrict__ pcc2,
    float* __restrict__ out)
{
    const int b = blockIdx.x;
    const int c = threadIdx.x;
    const float* p0 = tok + (size_t)b * TKN * CC + c;
    const float* p1 = tok + ((size_t)NB + b) * TKN * CC + c;
    float s0 = 0.0f, s1 = 0.0f;
    #pragma unroll 4
    for (int t = 0; t < TKN; ++t) { s0 += p0[t * CC]; s1 += p1[t * CC]; }
    const float a = pcc1[b], d = pcc2[b];
    const float mx = fmaxf(a, d);
    const float e0 = expf(a - mx), e1 = expf(d - mx);
    const float inv = 1.0f / (e0 + e1);
    out[(size_t)b * CC + c] = (e0 * inv * s0 + e1 * inv * s1) * (1.0f / TKN);
}

// ---------------------------------------------------------------------------
extern "C" void kernel_launch(void* const* d_in, const int* in_sizes, int n_in,
                              void* d_out, int out_size, void* d_ws, size_t ws_size,
                              hipStream_t stream)
{
    const float* edge_table = (const float*)d_in[0];
    const int*   src_eids   = (const int*)d_in[1];
    const int*   dst_eids   = (const int*)d_in[2];
    const int*   src2_e1    = (const int*)d_in[3];
    const int*   src2_e2    = (const int*)d_in[4];
    const int*   dst2_e1    = (const int*)d_in[5];
    const int*   dst2_e2    = (const int*)d_in[6];
    const float* dt_src     = (const float*)d_in[7];
    const float* dt_dst     = (const float*)d_in[8];
    const float* dt2_src    = (const float*)d_in[9];
    const float* dt2_dst    = (const float*)d_in[10];
    const float* pcc1       = (const float*)d_in[11];
    const float* pcc2       = (const float*)d_in[12];
    const float* time_w     = (const float*)d_in[13];
    const float* time_b     = (const float*)d_in[14];
    const float* proj_W     = (const float*)d_in[15];
    const float* proj_b     = (const float*)d_in[16];
    const float* eproj_W    = (const float*)d_in[17];
    const float* eproj_b    = (const float*)d_in[18];
    const float* mix_tln_g  = (const float*)d_in[19];
    const float* mix_tln_b  = (const float*)d_in[20];
    const float* mix_tW1    = (const float*)d_in[21];
    const float* mix_tb1    = (const float*)d_in[22];
    const float* mix_tW2    = (const float*)d_in[23];
    const float* mix_tb2    = (const float*)d_in[24];
    const float* mix_cln_g  = (const float*)d_in[25];
    const float* mix_cln_b  = (const float*)d_in[26];
    const float* mix_cW1    = (const float*)d_in[27];
    const float* mix_cb1    = (const float*)d_in[28];
    const float* mix_cW2    = (const float*)d_in[29];
    const float* mix_cb2    = (const float*)d_in[30];

    float* tok = (float*)d_ws;   // [2][NB][40][128] f32 = 84 MB

    build_tokens<<<dim3(NB, 2), 128, 0, stream>>>(
        edge_table, src_eids, dst_eids, src2_e1, src2_e2, dst2_e1, dst2_e2,
        dt_src, dt_dst, dt2_src, dt2_dst, time_w, time_b,
        proj_W, proj_b, eproj_W, eproj_b, tok);

    for (int layer = 0; layer < 2; ++layer) {
        token_mix<<<dim3(NB, 2), 128, 0, stream>>>(
            tok, layer, mix_tln_g, mix_tln_b, mix_tW1, mix_tb1, mix_tW2, mix_tb2);
        channel_mix<<<dim3(NB, 2), 128, 0, stream>>>(
            tok, layer, mix_cln_g, mix_cln_b, mix_cW1, mix_cb1, mix_cW2, mix_cb2);
    }

    combine<<<NB, 128, 0, stream>>>(tok, pcc1, pcc2, (float*)d_out);
}

// Round 2
// 2011.079 us; speedup vs baseline: 1.5302x; 1.5302x over previous
//
#include <hip/hip_runtime.h>
#include <hip/hip_bf16.h>
#include <math.h>

#define NB 2048      // batch
#define KN 20        // neighbors
#define DD 128       // edge feat dim
#define TT 100       // time dim
#define CC 128       // channels
#define TKN 40       // tokens (2K)
#define HTD 20       // token FFN hidden
#define HCD 512      // channel FFN hidden

#define AST 136      // A LDS stride (bf16 elems): +4 banks/row -> 2-way (free) frag reads
#define HST 144      // H LDS stride (bf16 elems): +8 banks/row -> conflict-free C-layout writes

typedef __attribute__((ext_vector_type(8))) short bf16x8;
typedef __attribute__((ext_vector_type(4))) float f32x4;

__device__ __forceinline__ float gelu_f(float x) {
    return 0.5f * x * (1.0f + erff(x * 0.70710678118654752f));
}

__device__ __forceinline__ unsigned short f2bf(float x) {
    __hip_bfloat16 h = __float2bfloat16(x);   // RNE
    return *reinterpret_cast<unsigned short*>(&h);
}

// ---------------------------------------------------------------------------
// Kernel 0: weight prep — bf16 + transpose to [n][k] rows for MFMA B-frags.
// grid 4 (mixer), block 256.
// ---------------------------------------------------------------------------
__global__ __launch_bounds__(256) void prep_weights(
    const float* __restrict__ cW1, const float* __restrict__ cW2,
    unsigned short* __restrict__ w1t, unsigned short* __restrict__ w2t)
{
    const int m = blockIdx.x;
    const int tid = threadIdx.x;
    // W1T[m][n][k] = cW1[m][k][n], n<512 k<128
    for (int idx = tid; idx < HCD * CC; idx += 256) {
        const int n = idx >> 7, k = idx & 127;
        w1t[(size_t)m * HCD * CC + idx] = f2bf(cW1[(size_t)m * CC * HCD + (size_t)k * HCD + n]);
    }
    // W2T[m][n][k] = cW2[m][k][n], n<128 k<512
    for (int idx = tid; idx < HCD * CC; idx += 256) {
        const int n = idx >> 9, k = idx & 511;
        w2t[(size_t)m * HCD * CC + idx] = f2bf(cW2[(size_t)m * HCD * CC + (size_t)k * CC + n]);
    }
}

// ---------------------------------------------------------------------------
// Kernel 1: build tokens (unchanged fp32 this round).
// ---------------------------------------------------------------------------
__global__ __launch_bounds__(128) void build_tokens(
    const float* __restrict__ edge_table,
    const int* __restrict__ src_eids, const int* __restrict__ dst_eids,
    const int* __restrict__ src2_e1, const int* __restrict__ src2_e2,
    const int* __restrict__ dst2_e1, const int* __restrict__ dst2_e2,
    const float* __restrict__ dt_src, const float* __restrict__ dt_dst,
    const float* __restrict__ dt2_src, const float* __restrict__ dt2_dst,
    const float* __restrict__ time_w, const float* __restrict__ time_b,
    const float* __restrict__ proj_W, const float* __restrict__ proj_b,
    const float* __restrict__ eproj_W, const float* __restrict__ eproj_b,
    float* __restrict__ tok)
{
    const int b = blockIdx.x;
    const int branch = blockIdx.y;
    const int tid = threadIdx.x;
    const int lane = tid & 63;
    const int wv = tid >> 6;
    const int Kdim = (branch == 0) ? (DD + TT) : (3 * DD + TT);
    const int FS = 488;

    __shared__ float feat[20 * 488];

    float* tokp = tok + ((size_t)branch * NB + b) * TKN * CC;

    for (int pass = 0; pass < 2; ++pass) {
        for (int tt = 0; tt < 10; ++tt) {
            const int tl = wv * 10 + tt;
            const int t = pass * 20 + tl;
            const int kk = (t < KN) ? t : (t - KN);
            float* f = feat + tl * FS;
            if (branch == 0) {
                int eid; float dt;
                if (t < KN) { eid = src_eids[b * KN + kk]; dt = dt_src[b * KN + kk]; }
                else        { eid = dst_eids[b * KN + kk]; dt = dt_dst[b * KN + kk]; }
                const float* er = edge_table + (size_t)eid * DD;
                f[lane] = er[lane];
                f[lane + 64] = er[lane + 64];
                const float msk = (eid == 0) ? 0.0f : 1.0f;
                f[DD + lane] = msk * cosf(dt * time_w[lane] + time_b[lane]);
                if (lane < TT - 64)
                    f[DD + 64 + lane] = msk * cosf(dt * time_w[64 + lane] + time_b[64 + lane]);
            } else {
                int e1, e2, e0; float dt;
                if (t < KN) {
                    e1 = src2_e1[b * KN + kk]; e2 = src2_e2[b * KN + kk];
                    e0 = src_eids[b * KN + kk]; dt = dt2_src[b * KN + kk];
                } else {
                    e1 = dst2_e1[b * KN + kk]; e2 = dst2_e2[b * KN + kk];
                    e0 = dst_eids[b * KN + kk]; dt = dt2_dst[b * KN + kk];
                }
                const float* r1 = edge_table + (size_t)e1 * DD;
                const float* r2 = edge_table + (size_t)e2 * DD;
                const float* r0 = edge_table + (size_t)e0 * DD;
                f[lane] = r1[lane];             f[lane + 64] = r1[lane + 64];
                f[DD + lane] = r2[lane];        f[DD + lane + 64] = r2[lane + 64];
                f[2 * DD + lane] = r0[lane];    f[2 * DD + lane + 64] = r0[lane + 64];
                const float msk = (e1 == 0) ? 0.0f : 1.0f;
                f[3 * DD + lane] = msk * cosf(dt * time_w[lane] + time_b[lane]);
                if (lane < TT - 64)
                    f[3 * DD + 64 + lane] = msk * cosf(dt * time_w[64 + lane] + time_b[64 + lane]);
            }
        }
        __syncthreads();

        const int tg = tid >> 5;
        const int cg = tid & 31;
        const int t5 = tg * 5;
        const int c4 = cg * 4;
        const float* Wp; const float* bp;
        if (branch == 0) { Wp = proj_W; bp = proj_b; }
        else { Wp = eproj_W + (size_t)pass * (3 * DD + TT) * CC; bp = eproj_b + pass * CC; }

        float acc[5][4];
        #pragma unroll
        for (int i = 0; i < 5; ++i)
            #pragma unroll
            for (int j = 0; j < 4; ++j) acc[i][j] = 0.0f;

        for (int kc = 0; kc < Kdim; kc += 4) {
            float w[4][4];
            #pragma unroll
            for (int kkk = 0; kkk < 4; ++kkk) {
                const float4 t4 = *(const float4*)(Wp + (size_t)(kc + kkk) * CC + c4);
                w[kkk][0] = t4.x; w[kkk][1] = t4.y; w[kkk][2] = t4.z; w[kkk][3] = t4.w;
            }
            #pragma unroll
            for (int i = 0; i < 5; ++i) {
                const float4 f4 = *(const float4*)(feat + (t5 + i) * FS + kc);
                const float fv[4] = {f4.x, f4.y, f4.z, f4.w};
                #pragma unroll
                for (int kkk = 0; kkk < 4; ++kkk)
                    #pragma unroll
                    for (int j = 0; j < 4; ++j)
                        acc[i][j] += fv[kkk] * w[kkk][j];
            }
        }
        #pragma unroll
        for (int i = 0; i < 5; ++i)
            #pragma unroll
            for (int j = 0; j < 4; ++j)
                tokp[(size_t)(pass * 20 + t5 + i) * CC + c4 + j] = acc[i][j] + bp[c4 + j];
        __syncthreads();
    }
}

// ---------------------------------------------------------------------------
// Kernel 2: token mixing (unchanged this round).
// ---------------------------------------------------------------------------
__global__ __launch_bounds__(128) void token_mix(
    float* __restrict__ tok, int layer,
    const float* __restrict__ tln_g, const float* __restrict__ tln_b,
    const float* __restrict__ tW1, const float* __restrict__ tb1,
    const float* __restrict__ tW2, const float* __restrict__ tb2)
{
    const int b = blockIdx.x;
    const int branch = blockIdx.y;
    const int m = branch * 2 + layer;
    const int c = threadIdx.x;

    const float* g  = tln_g + m * TKN;
    const float* bb = tln_b + m * TKN;
    const float* W1 = tW1 + (size_t)m * TKN * HTD;
    const float* b1 = tb1 + m * HTD;
    const float* W2 = tW2 + (size_t)m * HTD * TKN;
    const float* b2 = tb2 + m * TKN;

    float* xp = tok + ((size_t)branch * NB + b) * TKN * CC;

    float v[TKN];
    float s = 0.0f;
    #pragma unroll
    for (int k = 0; k < TKN; ++k) { v[k] = xp[k * CC + c]; s += v[k]; }
    const float mean = s * (1.0f / TKN);
    float vs = 0.0f;
    #pragma unroll
    for (int k = 0; k < TKN; ++k) { const float d = v[k] - mean; vs += d * d; }
    const float rinv = rsqrtf(vs * (1.0f / TKN) + 1e-5f);

    float h1[HTD];
    #pragma unroll
    for (int j = 0; j < HTD; ++j) h1[j] = b1[j];
    for (int k = 0; k < TKN; ++k) {
        const float nk = (v[k] - mean) * rinv * g[k] + bb[k];
        #pragma unroll
        for (int j = 0; j < HTD; ++j) h1[j] += nk * W1[k * HTD + j];
    }
    #pragma unroll
    for (int j = 0; j < HTD; ++j) h1[j] = gelu_f(h1[j]);

    for (int k = 0; k < TKN; ++k) {
        float s2 = b2[k];
        #pragma unroll
        for (int j = 0; j < HTD; ++j) s2 += h1[j] * W2[j * TKN + k];
        xp[k * CC + c] = v[k] + s2;
    }
}

// ---------------------------------------------------------------------------
// Kernel 3: channel mixing, bf16 MFMA.
// grid 1280 (128 rows each), block 256 = 4 waves, each wave owns 32 rows
// end-to-end -> NO __syncthreads. LDS is per-wave scratch.
// B-frags read straight from pre-transposed bf16 weights (L2-resident).
// ---------------------------------------------------------------------------
__global__ __launch_bounds__(256, 2) void channel_mix_mfma(
    float* __restrict__ tok, int layer,
    const float* __restrict__ cln_g, const float* __restrict__ cln_b,
    const unsigned short* __restrict__ w1t, const unsigned short* __restrict__ w2t,
    const float* __restrict__ cb1, const float* __restrict__ cb2)
{
    __shared__ __align__(16) short Abuf[4][32 * AST];   // 34816 B
    __shared__ __align__(16) short Hbuf[4][32 * HST];   // 36864 B

    const int tid = threadIdx.x;
    const int wv = tid >> 6;
    const int lane = tid & 63;
    const int l15 = lane & 15;
    const int q = lane >> 4;

    const int row0 = blockIdx.x * 128 + wv * 32;        // global token-row
    const int branch = row0 / (NB * TKN);               // rows per branch = 81920
    const int m = branch * 2 + layer;

    const float* g  = cln_g + m * CC;
    const float* bb = cln_b + m * CC;
    const unsigned short* W1 = w1t + (size_t)m * HCD * CC;
    const unsigned short* W2 = w2t + (size_t)m * HCD * CC;
    const float* B1 = cb1 + m * HCD;
    const float* B2 = cb2 + m * CC;

    float* X = tok + (size_t)row0 * CC;
    short* A = Abuf[wv];
    short* H = Hbuf[wv];

    const float g0 = g[lane], g1 = g[lane + 64];
    const float bb0 = bb[lane], bb1 = bb[lane + 64];

    // ---- LN of wave's 32 rows -> bf16 A tile ----
    for (int r = 0; r < 32; ++r) {
        const float x0 = X[r * CC + lane];
        const float x1 = X[r * CC + lane + 64];
        float s = x0 + x1, qq = x0 * x0 + x1 * x1;
        #pragma unroll
        for (int o = 32; o > 0; o >>= 1) {
            s += __shfl_xor(s, o);
            qq += __shfl_xor(qq, o);
        }
        const float mean = s * (1.0f / CC);
        const float rinv = rsqrtf(qq * (1.0f / CC) - mean * mean + 1e-5f);
        A[r * AST + lane]      = (short)f2bf((x0 - mean) * rinv * g0 + bb0);
        A[r * AST + lane + 64] = (short)f2bf((x1 - mean) * rinv * g1 + bb1);
    }

    f32x4 acc2[2][8];
    #pragma unroll
    for (int rt = 0; rt < 2; ++rt)
        #pragma unroll
        for (int nt = 0; nt < 8; ++nt) acc2[rt][nt] = (f32x4){0.f, 0.f, 0.f, 0.f};

    const short* Afrag = A + l15 * AST + q * 8;
    const short* Hfrag = H + l15 * HST + q * 8;

    for (int hc = 0; hc < 4; ++hc) {
        // ---- GEMM1: acc1 = LN(x) @ W1[:, hc*128 .. +128] ----
        f32x4 acc1[2][8];
        #pragma unroll
        for (int rt = 0; rt < 2; ++rt)
            #pragma unroll
            for (int nt = 0; nt < 8; ++nt) acc1[rt][nt] = (f32x4){0.f, 0.f, 0.f, 0.f};

        #pragma unroll
        for (int ks = 0; ks < 4; ++ks) {
            const bf16x8 a0 = *(const bf16x8*)(Afrag + ks * 32);
            const bf16x8 a1 = *(const bf16x8*)(Afrag + 16 * AST + ks * 32);
            #pragma unroll
            for (int nt = 0; nt < 8; ++nt) {
                const int n = hc * 128 + nt * 16 + l15;
                const bf16x8 b = *(const bf16x8*)(W1 + (size_t)n * CC + ks * 32 + q * 8);
                acc1[0][nt] = __builtin_amdgcn_mfma_f32_16x16x32_bf16(a0, b, acc1[0][nt], 0, 0, 0);
                acc1[1][nt] = __builtin_amdgcn_mfma_f32_16x16x32_bf16(a1, b, acc1[1][nt], 0, 0, 0);
            }
        }

        // ---- bias + gelu -> bf16 H tile (C-layout: col=l15, row=q*4+reg) ----
        #pragma unroll
        for (int nt = 0; nt < 8; ++nt) {
            const float b1v = B1[hc * 128 + nt * 16 + l15];
            #pragma unroll
            for (int rt = 0; rt < 2; ++rt)
                #pragma unroll
                for (int reg = 0; reg < 4; ++reg) {
                    const int rr = rt * 16 + q * 4 + reg;
                    H[rr * HST + nt * 16 + l15] =
                        (short)f2bf(gelu_f(acc1[rt][nt][reg] + b1v));
                }
        }

        // ---- GEMM2: acc2 += H @ W2[hc*128 .. +128, :] ----
        #pragma unroll
        for (int ks = 0; ks < 4; ++ks) {
            const bf16x8 h0 = *(const bf16x8*)(Hfrag + ks * 32);
            const bf16x8 h1 = *(const bf16x8*)(Hfrag + 16 * HST + ks * 32);
            #pragma unroll
            for (int nt = 0; nt < 8; ++nt) {
                const int n = nt * 16 + l15;
                const bf16x8 b = *(const bf16x8*)(W2 + (size_t)n * HCD + hc * 128 + ks * 32 + q * 8);
                acc2[0][nt] = __builtin_amdgcn_mfma_f32_16x16x32_bf16(h0, b, acc2[0][nt], 0, 0, 0);
                acc2[1][nt] = __builtin_amdgcn_mfma_f32_16x16x32_bf16(h1, b, acc2[1][nt], 0, 0, 0);
            }
        }
    }

    // ---- residual + bias, write back ----
    #pragma unroll
    for (int nt = 0; nt < 8; ++nt) {
        const int c = nt * 16 + l15;
        const float b2v = B2[c];
        #pragma unroll
        for (int rt = 0; rt < 2; ++rt)
            #pragma unroll
            for (int reg = 0; reg < 4; ++reg) {
                const int rr = rt * 16 + q * 4 + reg;
                X[rr * CC + c] += acc2[rt][nt][reg] + b2v;
            }
    }
}

// ---------------------------------------------------------------------------
// Kernel 4: token mean + pcc softmax blend.
// ---------------------------------------------------------------------------
__global__ __launch_bounds__(128) void combine(
    const float* __restrict__ tok,
    const float* __restrict__ pcc1, const float* __restrict__ pcc2,
    float* __restrict__ out)
{
    const int b = blockIdx.x;
    const int c = threadIdx.x;
    const float* p0 = tok + (size_t)b * TKN * CC + c;
    const float* p1 = tok + ((size_t)NB + b) * TKN * CC + c;
    float s0 = 0.0f, s1 = 0.0f;
    #pragma unroll 4
    for (int t = 0; t < TKN; ++t) { s0 += p0[t * CC]; s1 += p1[t * CC]; }
    const float a = pcc1[b], d = pcc2[b];
    const float mx = fmaxf(a, d);
    const float e0 = expf(a - mx), e1 = expf(d - mx);
    const float inv = 1.0f / (e0 + e1);
    out[(size_t)b * CC + c] = (e0 * inv * s0 + e1 * inv * s1) * (1.0f / TKN);
}

// ---------------------------------------------------------------------------
extern "C" void kernel_launch(void* const* d_in, const int* in_sizes, int n_in,
                              void* d_out, int out_size, void* d_ws, size_t ws_size,
                              hipStream_t stream)
{
    const float* edge_table = (const float*)d_in[0];
    const int*   src_eids   = (const int*)d_in[1];
    const int*   dst_eids   = (const int*)d_in[2];
    const int*   src2_e1    = (const int*)d_in[3];
    const int*   src2_e2    = (const int*)d_in[4];
    const int*   dst2_e1    = (const int*)d_in[5];
    const int*   dst2_e2    = (const int*)d_in[6];
    const float* dt_src     = (const float*)d_in[7];
    const float* dt_dst     = (const float*)d_in[8];
    const float* dt2_src    = (const float*)d_in[9];
    const float* dt2_dst    = (const float*)d_in[10];
    const float* pcc1       = (const float*)d_in[11];
    const float* pcc2       = (const float*)d_in[12];
    const float* time_w     = (const float*)d_in[13];
    const float* time_b     = (const float*)d_in[14];
    const float* proj_W     = (const float*)d_in[15];
    const float* proj_b     = (const float*)d_in[16];
    const float* eproj_W    = (const float*)d_in[17];
    const float* eproj_b    = (const float*)d_in[18];
    const float* mix_tln_g  = (const float*)d_in[19];
    const float* mix_tln_b  = (const float*)d_in[20];
    const float* mix_tW1    = (const float*)d_in[21];
    const float* mix_tb1    = (const float*)d_in[22];
    const float* mix_tW2    = (const float*)d_in[23];
    const float* mix_tb2    = (const float*)d_in[24];
    const float* mix_cln_g  = (const float*)d_in[25];
    const float* mix_cln_b  = (const float*)d_in[26];
    const float* mix_cW1    = (const float*)d_in[27];
    const float* mix_cb1    = (const float*)d_in[28];
    const float* mix_cW2    = (const float*)d_in[29];
    const float* mix_cb2    = (const float*)d_in[30];

    float* tok = (float*)d_ws;                                   // 83,886,080 B
    unsigned short* w1t = (unsigned short*)((char*)d_ws + 83886080);  // 524,288 B
    unsigned short* w2t = w1t + 4 * HCD * CC;                         // 524,288 B

    prep_weights<<<4, 256, 0, stream>>>(mix_cW1, mix_cW2, w1t, w2t);

    build_tokens<<<dim3(NB, 2), 128, 0, stream>>>(
        edge_table, src_eids, dst_eids, src2_e1, src2_e2, dst2_e1, dst2_e2,
        dt_src, dt_dst, dt2_src, dt2_dst, time_w, time_b,
        proj_W, proj_b, eproj_W, eproj_b, tok);

    for (int layer = 0; layer < 2; ++layer) {
        token_mix<<<dim3(NB, 2), 128, 0, stream>>>(
            tok, layer, mix_tln_g, mix_tln_b, mix_tW1, mix_tb1, mix_tW2, mix_tb2);
        channel_mix_mfma<<<1280, 256, 0, stream>>>(
            tok, layer, mix_cln_g, mix_cln_b, w1t, w2t, mix_cb1, mix_cb2);
    }

    combine<<<NB, 128, 0, stream>>>(tok, pcc1, pcc2, (float*)d_out);
}